// Round 12
// baseline (143.753 us; speedup 1.0000x reference)
//
#include <hip/hip_runtime.h>
#include <math.h>

typedef float v2f __attribute__((ext_vector_type(2)));

#define NSUP 512
#define DLAT 128
#define DHID 512
#define DIN  64
#define BR   16
#define NTILE 256   // 4096 / 16

// ---------------- prep: transposes + packs + planar support trig + norms ----------------
__global__ __launch_bounds__(512) void prep_kernel(
    const float* __restrict__ x, const float* __restrict__ W1, const float* __restrict__ W2,
    const float* __restrict__ support,
    float* __restrict__ W1T, float* __restrict__ W2T, float* __restrict__ xpack,
    float* __restrict__ scS, float* __restrict__ scC, float* __restrict__ scN,
    float* __restrict__ sn2)
{
    int idx = blockIdx.x * 512 + threadIdx.x;          // 512 x 512 = 262144
    {   // xpack[t][k][r] = x[t*16+r][k]   (writes coalesced)
        int t = idx >> 10, rem = idx & 1023, k = rem >> 4, r = rem & 15;
        xpack[idx] = x[((t << 4) | r) * DIN + k];
    }
    if (idx < DHID * DIN) {                 // W1 [512][64] -> W1T [64][512]
        int c = idx / DIN, k = idx % DIN;
        W1T[k * DHID + c] = W1[idx];
    }
    if (idx < DLAT * DHID) {
        int j = idx / DHID, k = idx % DHID;             // W2 -> W2T
        W2T[k * DLAT + j] = W2[idx];
        int s = idx & (NSUP - 1), i = idx >> 9;         // planar [i][s], writes coalesced
        float v = support[s * DLAT + i];
        scS[idx] = v;
        scC[idx] = cosf(0.5f * v);
        scN[idx] = sinf(0.5f * v);
    }
    if (idx < NSUP) {                       // ||s||^2 via float4
        const float4* sp = (const float4*)(support + idx * DLAT);
        float acc = 0.f;
        #pragma unroll 8
        for (int i4 = 0; i4 < DLAT / 4; i4++) {
            float4 v = sp[i4];
            acc = fmaf(v.x, v.x, fmaf(v.y, v.y, fmaf(v.z, v.z, fmaf(v.w, v.w, acc))));
        }
        sn2[idx] = acc;
    }
}

// ---------------- GEMM1: h = tanh(x @ W1^T + b1)  (s_load broadcast path) ----------------
__global__ __launch_bounds__(512) void gemm1_kernel(
    const float* __restrict__ W1T, const float* __restrict__ b1,
    const float* __restrict__ xpack, float* __restrict__ hpack)
{
    __shared__ float sh[DHID][17];                           // 34.8 KB
    const int t = blockIdx.x;
    const int c = threadIdx.x;
    const float* __restrict__ xr = xpack + t * (DIN * BR);   // uniform base -> s_load

    v2f acc[8];
    #pragma unroll
    for (int q = 0; q < 8; q++) acc[q] = (v2f)(0.f);

    for (int k = 0; k < DIN; k++) {
        float w = W1T[k * DHID + c];
        v2f wv = {w, w};
        const float* xk = xr + k * BR;                       // uniform -> s_load_dwordx16
        #pragma unroll
        for (int q = 0; q < 8; q++) {
            v2f xv = {xk[2 * q], xk[2 * q + 1]};
            acc[q] = __builtin_elementwise_fma(xv, wv, acc[q]);
        }
    }
    float bb = b1[c];
    #pragma unroll
    for (int q = 0; q < 8; q++) {
        sh[c][2 * q]     = tanhf(acc[q].x + bb);
        sh[c][2 * q + 1] = tanhf(acc[q].y + bb);
    }
    __syncthreads();
    float4* hp = (float4*)(hpack + t * (DHID * BR));
    #pragma unroll
    for (int w = threadIdx.x; w < DHID * BR / 4; w += 512) {
        int cc = w >> 2, r0 = (w & 3) * 4;
        hp[w] = make_float4(sh[cc][r0], sh[cc][r0 + 1], sh[cc][r0 + 2], sh[cc][r0 + 3]);
    }
}

// ---------------- GEMM2: latent + trig -> rowpack [t][i][rgrp4][{l4|a4|b4}] ----------------
__global__ __launch_bounds__(1024) void gemm2_kernel(
    const float* __restrict__ W2T, const float* __restrict__ b2,
    const float* __restrict__ hpack, float4* __restrict__ rowpack4, float* __restrict__ ln2s)
{
    __shared__ float part[8][DLAT][17];    // 69632 B
    __shared__ float tbuf[DLAT][49];       // 25088 B: [j][rp*6] = {l0,l1,a0,a1,b0,b1}
    __shared__ float l2red[16][2];

    const int t = blockIdx.x;
    const int j = threadIdx.x & (DLAT - 1);
    const int g = __builtin_amdgcn_readfirstlane(threadIdx.x >> 7);   // wave-uniform
    const float* __restrict__ hrow = hpack + t * (DHID * BR);

    v2f acc[8];
    #pragma unroll
    for (int q = 0; q < 8; q++) acc[q] = (v2f)(0.f);

    for (int kk = 0; kk < 64; kk++) {
        int k = g * 64 + kk;
        float w = W2T[k * DLAT + j];
        v2f wv = {w, w};
        const float* hk = hrow + k * BR;               // uniform -> s_load_dwordx16
        #pragma unroll
        for (int q = 0; q < 8; q++) {
            v2f hv = {hk[2 * q], hk[2 * q + 1]};
            acc[q] = __builtin_elementwise_fma(hv, wv, acc[q]);
        }
    }
    #pragma unroll
    for (int q = 0; q < 8; q++) {
        part[g][j][2 * q]     = acc[q].x;
        part[g][j][2 * q + 1] = acc[q].y;
    }
    __syncthreads();

    const int rp = g;                                   // row-pair 0..7, rows 2rp, 2rp+1
    float s0 = 0.f, s1 = 0.f;
    #pragma unroll
    for (int g2 = 0; g2 < 8; g2++) {
        s0 += part[g2][j][2 * rp];
        s1 += part[g2][j][2 * rp + 1];
    }
    float bb = b2[j];
    float l0 = s0 + bb, l1 = s1 + bb;

    tbuf[j][rp * 6 + 0] = l0;
    tbuf[j][rp * 6 + 1] = l1;
    tbuf[j][rp * 6 + 2] = cosf(0.5f * l0);
    tbuf[j][rp * 6 + 3] = cosf(0.5f * l1);
    tbuf[j][rp * 6 + 4] = sinf(0.5f * l0);
    tbuf[j][rp * 6 + 5] = sinf(0.5f * l1);

    // ||l||^2 per row
    const int wv = threadIdx.x >> 6;
    float v0 = l0 * l0, v1 = l1 * l1;
    for (int off = 32; off; off >>= 1) { v0 += __shfl_down(v0, off); v1 += __shfl_down(v1, off); }
    if ((threadIdx.x & 63) == 0) { l2red[wv][0] = v0; l2red[wv][1] = v1; }
    __syncthreads();

    if (threadIdx.x < BR) {
        int r = threadIdx.x, p = r >> 1, sel = r & 1;
        ln2s[t * BR + r] = l2red[2 * p][sel] + l2red[2 * p + 1][sel];
    }
    // coalesced store: 1536 float4/tile -> [i][rg][pq]: float4 idx = i*12 + rg*3 + pq
    for (int w4 = threadIdx.x; w4 < 1536; w4 += 1024) {
        int i = w4 / 12, c = w4 % 12, rg = c / 3, pq = c % 3;
        float vals[4];
        #pragma unroll
        for (int k = 0; k < 4; k++) {
            int r = rg * 4 + k;
            vals[k] = tbuf[i][(r >> 1) * 6 + pq * 2 + (r & 1)];
        }
        rowpack4[t * 1536 + w4] = make_float4(vals[0], vals[1], vals[2], vals[3]);
    }
}

// ---------------- stage B: 2D register tile + real occupancy ----------------
// grid 1024 = (256 row-tiles x 4 sup-quarters). block 256 = 4 waves, 4 blocks/CU.
// wave w owns sups [sq*128 + w*32, +32). lane = rr*16+sl: rows rr*4..+3 x sups base+sl*2..+1.
__global__ __launch_bounds__(256, 4) void kernelB(
    const float* __restrict__ scS, const float* __restrict__ scC, const float* __restrict__ scN,
    const float* __restrict__ sn2, const float* __restrict__ wts,
    const float* __restrict__ rowpackB, const float* __restrict__ ln2s,
    float* __restrict__ outpart)
{
    __shared__ float part[4][BR];

    const int b    = blockIdx.x;
    const int t    = b >> 2;
    const int sq   = b & 3;
    const int tid  = threadIdx.x;
    const int lane = tid & 63;
    const int w    = __builtin_amdgcn_readfirstlane(tid >> 6);   // 0..3
    const int rr   = lane >> 4;          // row-quad 0..3
    const int sl   = lane & 15;          // sup-slot 0..15
    const int sb   = sq * 128 + w * 32 + sl * 2;   // 2 consecutive sups

    const float* rp = rowpackB + t * (DLAT * 48) + rr * 12;   // [i][rgrp][{l4|a4|b4}]
    const float* pS = scS + sb;
    const float* pC = scC + sb;
    const float* pN = scN + sb;

    float dot[4][2], prod[4][2];
    #pragma unroll
    for (int r = 0; r < 4; r++)
        #pragma unroll
        for (int s = 0; s < 2; s++) { dot[r][s] = 0.f; prod[r][s] = 1.f; }

    #pragma unroll 2
    for (int i = 0; i < DLAT; i++) {
        float4 lq = *(const float4*)(rp + i * 48);        // rows: 4-aliased per wave
        float4 aq = *(const float4*)(rp + i * 48 + 4);
        float4 bq = *(const float4*)(rp + i * 48 + 8);
        float2 s2 = *(const float2*)(pS + i * NSUP);      // sups: coalesced
        float2 c2 = *(const float2*)(pC + i * NSUP);
        float2 n2 = *(const float2*)(pN + i * NSUP);
        float lv[4] = {lq.x, lq.y, lq.z, lq.w};
        float av[4] = {aq.x, aq.y, aq.z, aq.w};
        float bv[4] = {bq.x, bq.y, bq.z, bq.w};
        float sv[2] = {s2.x, s2.y};
        float cv[2] = {c2.x, c2.y};
        float nv[2] = {n2.x, n2.y};
        #pragma unroll
        for (int r = 0; r < 4; r++) {
            #pragma unroll
            for (int s = 0; s < 2; s++) {
                dot[r][s] = fmaf(lv[r], sv[s], dot[r][s]);
                float tt = fmaf(bv[r], nv[s], av[r] * cv[s]);
                prod[r][s] *= tt;
            }
        }
    }

    // ---- epilogue ----
    float2 snq = *(const float2*)(sn2 + sb);
    float2 wtq = *(const float2*)(wts + sb);
    float4 l2q = *(const float4*)(ln2s + t * BR + rr * 4);
    float snv[2] = {snq.x, snq.y};
    float wtv[2] = {wtq.x, wtq.y};
    float l2v[4] = {l2q.x, l2q.y, l2q.z, l2q.w};

    #pragma unroll
    for (int r = 0; r < 4; r++) {
        float acc = 0.f;
        #pragma unroll
        for (int s = 0; s < 2; s++) {
            float sq_ = l2v[r] + snv[s] - 2.f * dot[r][s];
            float p   = prod[r][s];
            acc += (0.5f * __expf(-sq_) + 0.5f * p * p) * wtv[s];
        }
        // reduce over 16 sl-lanes (within this rr segment)
        for (int off = 8; off; off >>= 1) acc += __shfl_down(acc, off);
        if (sl == 0) part[w][rr * 4 + r] = acc;
    }
    __syncthreads();
    if (tid < BR) {
        float o = (part[0][tid] + part[1][tid]) + (part[2][tid] + part[3][tid]);
        outpart[sq * (NTILE * BR) + t * BR + tid] = o;
    }
}

// ---------------- combine: out = sum of 4 support-quarter partials ----------------
__global__ __launch_bounds__(256) void combine_kernel(
    const float* __restrict__ outpart, float* __restrict__ out)
{
    int i = blockIdx.x * 256 + threadIdx.x;           // 0..4095
    out[i] = (outpart[i] + outpart[NTILE * BR + i])
           + (outpart[2 * NTILE * BR + i] + outpart[3 * NTILE * BR + i]);
}

// ---------------- launch ----------------
extern "C" void kernel_launch(void* const* d_in, const int* in_sizes, int n_in,
                              void* d_out, int out_size, void* d_ws, size_t ws_size,
                              hipStream_t stream) {
    const float* x       = (const float*)d_in[0];
    const float* W1      = (const float*)d_in[1];
    const float* b1      = (const float*)d_in[2];
    const float* W2      = (const float*)d_in[3];
    const float* b2      = (const float*)d_in[4];
    const float* support = (const float*)d_in[5];
    const float* wts     = (const float*)d_in[6];
    float* out = (float*)d_out;

    float* ws      = (float*)d_ws;
    float* W1T     = ws;                        // 32768
    float* W2T     = W1T + 32768;               // 65536
    float* xpack   = W2T + 65536;               // 262144
    float* hpack   = xpack + 262144;            // 2097152   (16B-aligned offset)
    float* rowpack = hpack + 2097152;           // 1572864   (16B-aligned offset)
    float* ln2s    = rowpack + 1572864;         // 4096
    float* sn2     = ln2s + 4096;               // 512
    float* scS     = sn2 + 512;                 // 65536 (16B-aligned offset)
    float* scC     = scS + 65536;               // 65536
    float* scN     = scC + 65536;               // 65536
    float* outpart = scN + 65536;               // 16384

    prep_kernel <<<512,  512, 0, stream>>>(x, W1, W2, support, W1T, W2T, xpack,
                                           scS, scC, scN, sn2);
    gemm1_kernel<<<NTILE, 512, 0, stream>>>(W1T, b1, xpack, hpack);
    gemm2_kernel<<<NTILE, 1024, 0, stream>>>(W2T, b2, hpack, (float4*)rowpack, ln2s);
    kernelB     <<<NTILE * 4, 256, 0, stream>>>(scS, scC, scN, sn2, wts,
                                                rowpack, ln2s, outpart);
    combine_kernel<<<16, 256, 0, stream>>>(outpart, out);
}